// Round 7
// baseline (1120.339 us; speedup 1.0000x reference)
//
#include <hip/hip_runtime.h>
#include <hip/hip_bf16.h>
#include <stdint.h>

typedef __bf16 bf16_t;
typedef __bf16 bf16x4 __attribute__((ext_vector_type(4)));
typedef __bf16 bf16x8 __attribute__((ext_vector_type(8)));
typedef bf16x8 bf16x8u __attribute__((aligned(8)));   // 8-byte-aligned view (stride-36 rows)
typedef float  f32x4  __attribute__((ext_vector_type(4)));

#define SCALE 0.17677669529663687f   // (192/6)^-0.5

__device__ __forceinline__ bf16_t tobf(float f) { return (bf16_t)f; }

__global__ void cvt_weights(const float* __restrict__ qkv_w,
                            const float* __restrict__ proj_w,
                            bf16_t* __restrict__ qkv_wb,
                            bf16_t* __restrict__ proj_wb)
{
  int i = blockIdx.x * 256 + threadIdx.x;
  if (i < 576 * 192) qkv_wb[i] = tobf(qkv_w[i]);
  if (i < 192 * 192) proj_wb[i] = tobf(proj_w[i]);
}

// GEMM1 tile body. TYP, G are compile-time literals. Destination planes are
// LOCAL to the current head-group: global head h_ maps to plane h_ - 3*G.
#define G1_TILE(NTV, WF, TYP, G)                                                \
    {                                                                           \
      const int nt_  = (NTV);                                                   \
      if ((TYP) < 2) {                                                          \
        float4 qb4 = *(const float4*)(qkv_b + nt_ * 16 + lg * 4);               \
        const int cc_ = (nt_ - (TYP) * 12) * 16 + lg * 4;                       \
        const int hp_ = (cc_ >> 5) - 3 * (G), dd_ = cc_ & 31;                   \
        bf16_t* dst_ = &shead[hp_][(TYP) * 2304 + dd_];                         \
        f32x4 a0 = fzero, a1 = fzero;                                           \
        _Pragma("unroll")                                                       \
        for (int kk = 0; kk < 6; ++kk) {                                        \
          a0 = __builtin_amdgcn_mfma_f32_16x16x32_bf16((WF)[kk], xb0[kk], a0, 0, 0, 0); \
          a1 = __builtin_amdgcn_mfma_f32_16x16x32_bf16((WF)[kk], xb1[kk], a1, 0, 0, 0); \
        }                                                                       \
        bf16x4 p0_ = { tobf(a0[0] + qb4.x), tobf(a0[1] + qb4.y),                \
                       tobf(a0[2] + qb4.z), tobf(a0[3] + qb4.w) };              \
        bf16x4 p1_ = { tobf(a1[0] + qb4.x), tobf(a1[1] + qb4.y),                \
                       tobf(a1[2] + qb4.z), tobf(a1[3] + qb4.w) };              \
        *(bf16x4*)&dst_[((half * 2 + 0) * 16 + li) * 36] = p0_;                 \
        *(bf16x4*)&dst_[((half * 2 + 1) * 16 + li) * 36] = p1_;                 \
      } else {                                                                  \
        const float vb_ = qkv_b[nt_ * 16 + li];                                 \
        const int cc_ = (nt_ - 24) * 16 + li;                                   \
        const int hp_ = (cc_ >> 5) - 3 * (G), dd_ = cc_ & 31;                   \
        bf16_t* dst_ = &svt[hp_][dd_ * 72];                                     \
        f32x4 a0 = fzero, a1 = fzero;                                           \
        _Pragma("unroll")                                                       \
        for (int kk = 0; kk < 6; ++kk) {                                        \
          a0 = __builtin_amdgcn_mfma_f32_16x16x32_bf16(xb0[kk], (WF)[kk], a0, 0, 0, 0); \
          a1 = __builtin_amdgcn_mfma_f32_16x16x32_bf16(xb1[kk], (WF)[kk], a1, 0, 0, 0); \
        }                                                                       \
        bf16x4 p0_ = { tobf(a0[0] + vb_), tobf(a0[1] + vb_),                    \
                       tobf(a0[2] + vb_), tobf(a0[3] + vb_) };                  \
        bf16x4 p1_ = { tobf(a1[0] + vb_), tobf(a1[1] + vb_),                    \
                       tobf(a1[2] + vb_), tobf(a1[3] + vb_) };                  \
        *(bf16x4*)&dst_[(half * 2 + 0) * 16 + lg * 4] = p0_;                    \
        *(bf16x4*)&dst_[(half * 2 + 1) * 16 + lg * 4] = p1_;                    \
      }                                                                         \
    }

// One head-group of GEMM1: wave w computes q tile 6G+w, k tile 12+6G+w,
// v tile 24+6G+w (18 tiles / 6 waves, perfectly balanced). Weights streamed
// from L2 (qkv_wb = 221KB, L2-resident).
#define G1_GROUP(G)                                                             \
  _Pragma("unroll")                                                             \
  for (int half = 0; half < 2; ++half) {                                        \
    bf16x8 xb0[6], xb1[6];                                                      \
    _Pragma("unroll")                                                           \
    for (int kk = 0; kk < 6; ++kk) {                                            \
      xb0[kk] = *(const bf16x8*)&sx[((half * 2 + 0) * 16 + li) * 200 + kk * 32 + lg * 8]; \
      xb1[kk] = *(const bf16x8*)&sx[((half * 2 + 1) * 16 + li) * 200 + kk * 32 + lg * 8]; \
    }                                                                           \
    {                                                                           \
      bf16x8 wq[6];                                                             \
      const bf16_t* wr = qkv_wb + (size_t)((6 * (G) + wave) * 16 + li) * 192 + lg * 8; \
      _Pragma("unroll")                                                         \
      for (int kk = 0; kk < 6; ++kk) wq[kk] = *(const bf16x8*)(wr + kk * 32);   \
      G1_TILE(6 * (G) + wave, wq, 0, G)                                         \
    }                                                                           \
    {                                                                           \
      bf16x8 wk[6];                                                             \
      const bf16_t* wr = qkv_wb + (size_t)((12 + 6 * (G) + wave) * 16 + li) * 192 + lg * 8; \
      _Pragma("unroll")                                                         \
      for (int kk = 0; kk < 6; ++kk) wk[kk] = *(const bf16x8*)(wr + kk * 32);   \
      G1_TILE(12 + 6 * (G) + wave, wk, 1, G)                                    \
    }                                                                           \
    {                                                                           \
      bf16x8 wv[6];                                                             \
      const bf16_t* wr = qkv_wb + (size_t)((24 + 6 * (G) + wave) * 16 + li) * 192 + lg * 8; \
      _Pragma("unroll")                                                         \
      for (int kk = 0; kk < 6; ++kk) wv[kk] = *(const bf16x8*)(wr + kk * 32);   \
      G1_TILE(24 + 6 * (G) + wave, wv, 2, G)                                    \
    }                                                                           \
  }

// One attention unit: QK^T + softmax(+mask) + PV. Results returned as two
// bf16x4 (output rows nt*16+li, cols [c0, c0+4) and [c0+16, c0+20)); the
// CALLER decides whether to hold them in regs or store to LDS.
__device__ __forceinline__ void attn_unit(
    const bf16_t* __restrict__ sq, const bf16_t* __restrict__ sk,
    const bf16_t* __restrict__ svh, bf16_t* __restrict__ P,
    const float4* __restrict__ mr, int li, int lg, int nt,
    bf16x4& r0, bf16x4& r1)
{
  const f32x4 fzero = {0.f, 0.f, 0.f, 0.f};
  bf16x8 qf = *(const bf16x8u*)&sq[(nt * 16 + li) * 36 + lg * 8];
  f32x4 sacc[4];
#pragma unroll
  for (int mt = 0; mt < 4; ++mt) {
    bf16x8 kf = *(const bf16x8u*)&sk[(mt * 16 + li) * 36 + lg * 8];
    sacc[mt] = __builtin_amdgcn_mfma_f32_16x16x32_bf16(kf, qf, fzero, 0, 0, 0);
  }
  float vals[16];
  float rmax = -3.0e38f;
#pragma unroll
  for (int mt = 0; mt < 4; ++mt)
#pragma unroll
    for (int r = 0; r < 4; ++r) {
      float v = sacc[mt][r] * SCALE + ((const float*)&mr[mt])[r];
      vals[mt * 4 + r] = v;
      rmax = fmaxf(rmax, v);
    }
  rmax = fmaxf(rmax, __shfl_xor(rmax, 16));
  rmax = fmaxf(rmax, __shfl_xor(rmax, 32));
  float rsum = 0.f;
#pragma unroll
  for (int e = 0; e < 16; ++e) {
    float t = __expf(vals[e] - rmax);
    vals[e] = t;
    rsum += t;
  }
  rsum += __shfl_xor(rsum, 16);
  rsum += __shfl_xor(rsum, 32);
  const float inv = __builtin_amdgcn_rcpf(rsum);
#pragma unroll
  for (int mt = 0; mt < 4; ++mt) {
    bf16x4 p = { tobf(vals[mt * 4 + 0] * inv), tobf(vals[mt * 4 + 1] * inv),
                 tobf(vals[mt * 4 + 2] * inv), tobf(vals[mt * 4 + 3] * inv) };
    *(bf16x4*)&P[li * 72 + mt * 16 + lg * 4] = p;
  }
  __asm__ volatile("s_waitcnt lgkmcnt(0)" ::: "memory");
  f32x4 o0 = fzero, o1 = fzero;
#pragma unroll
  for (int ks = 0; ks < 2; ++ks) {
    bf16x8 pfr = *(const bf16x8*)&P[li * 72 + ks * 32 + lg * 8];
    bf16x8 v0  = *(const bf16x8*)&svh[li * 72 + ks * 32 + lg * 8];
    bf16x8 v1  = *(const bf16x8*)&svh[(16 + li) * 72 + ks * 32 + lg * 8];
    o0 = __builtin_amdgcn_mfma_f32_16x16x32_bf16(v0, pfr, o0, 0, 0, 0);
    o1 = __builtin_amdgcn_mfma_f32_16x16x32_bf16(v1, pfr, o1, 0, 0, 0);
  }
  r0 = (bf16x4){ tobf(o0[0]), tobf(o0[1]), tobf(o0[2]), tobf(o0[3]) };
  r1 = (bf16x4){ tobf(o1[0]), tobf(o1[1]), tobf(o1[2]), tobf(o1[3]) };
}

// Persistent fused kernel: grid 512 (2 blocks/CU!), 384 threads (6 waves),
// 16 windows/block. LDS = 80896 B <= 81920 -> TWO blocks co-resident per CU:
// 12 waves/CU, and — the point — cross-block overlap: while one block drains
// a barrier or waits on its HBM x-burst, the other block computes. This
// attacks the latency-boundedness (all pipes <40%) that within-block
// scheduling (R2-R6) could not.
//
// LDS diet via HEAD-SPLIT: shead/svt sized for 3 heads, used twice per window
// (group 0 = heads 0-2, group 1 = heads 3-5). Single x buffer; group-0 attn
// output held in 8 regs until x is dead (barrier A1), group-1 written direct.
// Work balanced at 6 waves: G1 3 tiles/wave/group, attn 2 units/wave/group,
// G2 2 adjacent ct tiles/wave (full 128B output sectors).
//
// Register discipline (R2-R6 lesson): allocator targets 2-blocks'-worth of
// VGPRs no matter what; here that is 512/3 ~= 168. Peak live-set kept ~120
// (no persistent hoists; wp loaded per-iter; pf issued after G1b).
__global__ __launch_bounds__(384, 3) void winattn_fused(
    const float* __restrict__ x,        // [8192,64,192]
    const float* __restrict__ mask,     // [4096,64,64]
    const float* __restrict__ qkv_b,    // [576]
    const float* __restrict__ proj_b,   // [192]
    const bf16_t* __restrict__ qkv_wb,  // [576,192] bf16
    const bf16_t* __restrict__ proj_wb, // [192,192] bf16
    float* __restrict__ out)            // [8192,64,192]
{
  // LDS: 25600 + 27648 + 13824 + 13824 = 80896 B  (2 blocks/CU)
  __shared__ __align__(16) bf16_t sx[64 * 200];          // x staging / attn-out
  __shared__ __align__(16) bf16_t shead[3][2 * 64 * 36]; // per LOCAL head: q[64][36], k[64][36]
  __shared__ __align__(16) bf16_t svt[3][32 * 72];       // per LOCAL head vT [32][72]
  __shared__ __align__(16) bf16_t spw[6][16 * 72];       // per wave P scratch

  const int tid  = threadIdx.x;
  const int wave = tid >> 6;
  const int lane = tid & 63;
  const int li   = lane & 15;
  const int lg   = lane >> 4;
  const int bid  = blockIdx.x;
  const f32x4 fzero = {0.f, 0.f, 0.f, 0.f};

  // ---- prologue: stage window bid (it=0) into sx ----
  {
    const float4* src = (const float4*)(x + (size_t)bid * 12288);
#pragma unroll
    for (int j = 0; j < 8; ++j) {
      float4 v = src[tid + 384 * j];
      int id = tid + 384 * j;
      int sr = id / 48, sc = (id % 48) * 4;
      bf16x4 p = { tobf(v.x), tobf(v.y), tobf(v.z), tobf(v.w) };
      *(bf16x4*)&sx[sr * 200 + sc] = p;
    }
  }
  __syncthreads();

  for (int it = 0; it < 16; ++it) {
    const int b = bid + 512 * (it >> 1) + 4096 * (it & 1);  // mask-paired order
    const bool hasNext = (it < 15);

    // ---- G1a: qkv for heads 0-2 ----
    G1_GROUP(0)

    // mask burst for this wave's 2 units (rows depend on nt only -> same rows
    // both groups; reloaded per group, 2nd load is L2-hit)
    float4 mreg[2][4];
    {
      const float* maskw = mask + (size_t)(b & 4095) * 4096;
#pragma unroll
      for (int uu = 0; uu < 2; ++uu) {
        const int ntu = (wave * 2 + uu) & 3;
        const float* mrow = maskw + (ntu * 16 + li) * 64 + lg * 4;
#pragma unroll
        for (int mt = 0; mt < 4; ++mt) mreg[uu][mt] = *(const float4*)(mrow + mt * 16);
      }
    }
    __syncthreads();   // A0: group-0 qkv ready

    // ---- attn group 0: hold output in regs (x in sx still live for G1b) ----
    bf16x4 og[2][2];
#pragma unroll
    for (int uu = 0; uu < 2; ++uu) {
      const int unit = wave * 2 + uu;
      const int hl = unit >> 2, nt = unit & 3;
      attn_unit(&shead[hl][0], &shead[hl][2304], &svt[hl][0], spw[wave],
                mreg[uu], li, lg, nt, og[uu][0], og[uu][1]);
    }
    __syncthreads();   // B0: group-0 shead/svt dead -> G1b may overwrite

    // ---- G1b: qkv for heads 3-5 (x still live, read again) ----
    G1_GROUP(1)

    // reload mask (L2-hit) + issue next-x prefetch (latency covered by
    // attn1 + G2; pf regs live only until the write after barrier D)
    {
      const float* maskw = mask + (size_t)(b & 4095) * 4096;
#pragma unroll
      for (int uu = 0; uu < 2; ++uu) {
        const int ntu = (wave * 2 + uu) & 3;
        const float* mrow = maskw + (ntu * 16 + li) * 64 + lg * 4;
#pragma unroll
        for (int mt = 0; mt < 4; ++mt) mreg[uu][mt] = *(const float4*)(mrow + mt * 16);
      }
    }
    float4 pf[8];
    if (hasNext) {
      const int bn = bid + 512 * ((it + 1) >> 1) + 4096 * ((it + 1) & 1);
      const float4* src = (const float4*)(x + (size_t)bn * 12288);
#pragma unroll
      for (int j = 0; j < 8; ++j) pf[j] = src[tid + 384 * j];
    }
    __syncthreads();   // A1: group-1 qkv ready AND x fully consumed (dead)

    // write group-0 attn output into sx (x dead now); cols h*32, h = 0..2
#pragma unroll
    for (int uu = 0; uu < 2; ++uu) {
      const int unit = wave * 2 + uu;
      const int hl = unit >> 2, nt = unit & 3;
      bf16_t* so = &sx[(nt * 16 + li) * 200 + hl * 32 + lg * 4];
      *(bf16x4*)&so[0]  = og[uu][0];
      *(bf16x4*)&so[16] = og[uu][1];
    }

    // ---- attn group 1: write output directly (cols (3+h)*32) ----
#pragma unroll
    for (int uu = 0; uu < 2; ++uu) {
      const int unit = wave * 2 + uu;
      const int hl = unit >> 2, nt = unit & 3;
      bf16x4 r0, r1;
      attn_unit(&shead[hl][0], &shead[hl][2304], &svt[hl][0], spw[wave],
                mreg[uu], li, lg, nt, r0, r1);
      bf16_t* so = &sx[(nt * 16 + li) * 200 + (3 + hl) * 32 + lg * 4];
      *(bf16x4*)&so[0]  = r0;
      *(bf16x4*)&so[16] = r1;
    }
    __syncthreads();   // C: all attn-out in sx

    // ---- GEMM2: out = so @ proj_w^T + proj_b ----
    // wave w -> ct pair {2w, 2w+1}, all 4 row-tiles: full 128B sectors.
    // proj weights loaded per-iter (L2-hot, 73KB), live only through G2.
    {
      float* ob = out + (size_t)b * 12288;
      bf16x8 wp0[6], wp1[6];
      {
        const bf16_t* wr0 = proj_wb + (size_t)((2 * wave + 0) * 16 + li) * 192 + lg * 8;
        const bf16_t* wr1 = proj_wb + (size_t)((2 * wave + 1) * 16 + li) * 192 + lg * 8;
#pragma unroll
        for (int kk = 0; kk < 6; ++kk) {
          wp0[kk] = *(const bf16x8*)(wr0 + kk * 32);
          wp1[kk] = *(const bf16x8*)(wr1 + kk * 32);
        }
      }
      const float4 pb0 = *(const float4*)(proj_b + (2 * wave + 0) * 16 + lg * 4);
      const float4 pb1 = *(const float4*)(proj_b + (2 * wave + 1) * 16 + lg * 4);
#pragma unroll
      for (int mt = 0; mt < 4; ++mt) {
        bf16x8 sb[6];
#pragma unroll
        for (int kk = 0; kk < 6; ++kk)
          sb[kk] = *(const bf16x8*)&sx[(mt * 16 + li) * 200 + kk * 32 + lg * 8];
        f32x4 a0 = fzero, a1 = fzero;
#pragma unroll
        for (int kk = 0; kk < 6; ++kk) {
          a0 = __builtin_amdgcn_mfma_f32_16x16x32_bf16(wp0[kk], sb[kk], a0, 0, 0, 0);
          a1 = __builtin_amdgcn_mfma_f32_16x16x32_bf16(wp1[kk], sb[kk], a1, 0, 0, 0);
        }
        float4 o0 = { a0[0] + pb0.x, a0[1] + pb0.y, a0[2] + pb0.z, a0[3] + pb0.w };
        float4 o1 = { a1[0] + pb1.x, a1[1] + pb1.y, a1[2] + pb1.z, a1[3] + pb1.w };
        float* orow = ob + (size_t)(mt * 16 + li) * 192 + (2 * wave) * 16 + lg * 4;
        *(float4*)(orow)      = o0;
        *(float4*)(orow + 16) = o1;
      }
    }

    if (hasNext) {
      __syncthreads();   // D: all G2 reads of sx complete
#pragma unroll
      for (int j = 0; j < 8; ++j) {
        int id = tid + 384 * j;
        int sr = id / 48, sc = (id % 48) * 4;
        bf16x4 p = { tobf(pf[j].x), tobf(pf[j].y), tobf(pf[j].z), tobf(pf[j].w) };
        *(bf16x4*)&sx[sr * 200 + sc] = p;
      }
      __syncthreads();   // S: next x staged
    }
  }
}

extern "C" void kernel_launch(void* const* d_in, const int* in_sizes, int n_in,
                              void* d_out, int out_size, void* d_ws, size_t ws_size,
                              hipStream_t stream) {
  const float* x      = (const float*)d_in[0];
  const float* mask   = (const float*)d_in[1];
  const float* qkv_w  = (const float*)d_in[2];
  const float* qkv_b  = (const float*)d_in[3];
  const float* proj_w = (const float*)d_in[4];
  const float* proj_b = (const float*)d_in[5];
  float* out = (float*)d_out;

  bf16_t* qkv_wb  = (bf16_t*)d_ws;
  bf16_t* proj_wb = qkv_wb + 576 * 192;

  cvt_weights<<<432, 256, 0, stream>>>(qkv_w, proj_w, qkv_wb, proj_wb);
  winattn_fused<<<512, 384, 0, stream>>>(x, mask, qkv_b, proj_b, qkv_wb, proj_wb, out);
}

// Round 8
// 877.212 us; speedup vs baseline: 1.2772x; 1.2772x over previous
//
#include <hip/hip_runtime.h>
#include <hip/hip_bf16.h>
#include <stdint.h>

typedef __bf16 bf16_t;
typedef __bf16 bf16x4 __attribute__((ext_vector_type(4)));
typedef __bf16 bf16x8 __attribute__((ext_vector_type(8)));
typedef bf16x8 bf16x8u __attribute__((aligned(8)));   // 8-byte-aligned view (stride-36 rows)
typedef float  f32x4  __attribute__((ext_vector_type(4)));

#define SCALE 0.17677669529663687f   // (192/6)^-0.5

__device__ __forceinline__ bf16_t tobf(float f) { return (bf16_t)f; }
__device__ __forceinline__ unsigned short bfbits(bf16_t v) {
  union { bf16_t f; unsigned short s; } u; u.f = v; return u.s;
}

__global__ void cvt_weights(const float* __restrict__ qkv_w,
                            const float* __restrict__ proj_w,
                            bf16_t* __restrict__ qkv_wb,
                            bf16_t* __restrict__ proj_wb)
{
  int i = blockIdx.x * 256 + threadIdx.x;
  if (i < 576 * 192) qkv_wb[i] = tobf(qkv_w[i]);
  if (i < 192 * 192) proj_wb[i] = tobf(proj_w[i]);
}

// ---- GEMM1 tile: one 16-col qkv tile for 2 token-row-tiles (half) ----
// t in [0,18) per group: typ = t/6 (0=q,1=k,2=v), j = t%6, nt = typ*12+6G+j.
// Wave-uniform branch. Writes into group-LOCAL shead/svt planes.
__device__ __forceinline__ void g1_tile(
    int t, int G, int half, int li, int lg,
    const bf16x8* xb0, const bf16x8* xb1,
    bf16_t (*shead)[2 * 64 * 36], bf16_t (*svt)[32 * 72],
    const bf16_t* __restrict__ qkv_wb, const float* __restrict__ qkv_b)
{
  const f32x4 fzero = {0.f, 0.f, 0.f, 0.f};
  const int typ = t / 6, j = t % 6;
  const int nt  = typ * 12 + 6 * G + j;
  bf16x8 wf[6];
  const bf16_t* wr = qkv_wb + (size_t)(nt * 16 + li) * 192 + lg * 8;
#pragma unroll
  for (int kk = 0; kk < 6; ++kk) wf[kk] = *(const bf16x8*)(wr + kk * 32);
  f32x4 a0 = fzero, a1 = fzero;
  if (typ < 2) {
#pragma unroll
    for (int kk = 0; kk < 6; ++kk) {
      a0 = __builtin_amdgcn_mfma_f32_16x16x32_bf16(wf[kk], xb0[kk], a0, 0, 0, 0);
      a1 = __builtin_amdgcn_mfma_f32_16x16x32_bf16(wf[kk], xb1[kk], a1, 0, 0, 0);
    }
    float4 qb4 = *(const float4*)(qkv_b + nt * 16 + lg * 4);
    const int cc = j * 16 + lg * 4;
    const int hp = cc >> 5, dd = cc & 31;
    bf16_t* dst = &shead[hp][typ * 2304 + dd];
    bf16x4 p0 = { tobf(a0[0] + qb4.x), tobf(a0[1] + qb4.y),
                  tobf(a0[2] + qb4.z), tobf(a0[3] + qb4.w) };
    bf16x4 p1 = { tobf(a1[0] + qb4.x), tobf(a1[1] + qb4.y),
                  tobf(a1[2] + qb4.z), tobf(a1[3] + qb4.w) };
    *(bf16x4*)&dst[((half * 2 + 0) * 16 + li) * 36] = p0;
    *(bf16x4*)&dst[((half * 2 + 1) * 16 + li) * 36] = p1;
  } else {
#pragma unroll
    for (int kk = 0; kk < 6; ++kk) {
      a0 = __builtin_amdgcn_mfma_f32_16x16x32_bf16(xb0[kk], wf[kk], a0, 0, 0, 0);
      a1 = __builtin_amdgcn_mfma_f32_16x16x32_bf16(xb1[kk], wf[kk], a1, 0, 0, 0);
    }
    const float vb = qkv_b[nt * 16 + li];
    const int cc = j * 16 + li;
    const int hp = cc >> 5, dd = cc & 31;
    bf16_t* dst = &svt[hp][dd * 72];
    bf16x4 p0 = { tobf(a0[0] + vb), tobf(a0[1] + vb),
                  tobf(a0[2] + vb), tobf(a0[3] + vb) };
    bf16x4 p1 = { tobf(a1[0] + vb), tobf(a1[1] + vb),
                  tobf(a1[2] + vb), tobf(a1[3] + vb) };
    *(bf16x4*)&dst[(half * 2 + 0) * 16 + lg * 4] = p0;
    *(bf16x4*)&dst[(half * 2 + 1) * 16 + lg * 4] = p1;
  }
}

// One head-group of GEMM1: 18 tiles over 8 waves (waves 0-1 take a 3rd tile).
#define G1_GROUP(G)                                                             \
  _Pragma("unroll")                                                             \
  for (int half = 0; half < 2; ++half) {                                        \
    bf16x8 xb0[6], xb1[6];                                                      \
    _Pragma("unroll")                                                           \
    for (int kk = 0; kk < 6; ++kk) {                                            \
      xb0[kk] = *(const bf16x8*)&sx[((half * 2 + 0) * 16 + li) * 200 + kk * 32 + lg * 8]; \
      xb1[kk] = *(const bf16x8*)&sx[((half * 2 + 1) * 16 + li) * 200 + kk * 32 + lg * 8]; \
    }                                                                           \
    g1_tile(wave,     (G), half, li, lg, xb0, xb1, shead, svt, qkv_wb, qkv_b);  \
    g1_tile(wave + 8, (G), half, li, lg, xb0, xb1, shead, svt, qkv_wb, qkv_b);  \
    if (wave < 2)                                                               \
      g1_tile(wave + 16, (G), half, li, lg, xb0, xb1, shead, svt, qkv_wb, qkv_b); \
  }

// ---- attention unit: QK^T + softmax(+mask) + PV, P transposed IN-REGISTER ----
// C/D layout gives lane (li,lg): P[q=li][k=16mt+4lg+r]. The PV B-operand needs
// P[q=li][k=32ks+8lg+e]. Fixed lane-exchange among the 4 lg groups:
// source lane = b4*32 + jhi*16 + li (b4 = target lane bit4), register
// pk[2ks+b5][j&1] (b5 = target lane bit5). 16 ds_bpermute + 8 selects,
// no LDS buffer, no write->read hazard.
__device__ __forceinline__ void attn_unit(
    const bf16_t* __restrict__ sq, const bf16_t* __restrict__ sk,
    const bf16_t* __restrict__ svh,
    const float4* __restrict__ mr, int li, int lg, int nt,
    int addr0, int addr1, bool hi, bf16x4& r0, bf16x4& r1)
{
  const f32x4 fzero = {0.f, 0.f, 0.f, 0.f};
  bf16x8 qf = *(const bf16x8u*)&sq[(nt * 16 + li) * 36 + lg * 8];
  f32x4 sacc[4];
#pragma unroll
  for (int mt = 0; mt < 4; ++mt) {
    bf16x8 kf = *(const bf16x8u*)&sk[(mt * 16 + li) * 36 + lg * 8];
    sacc[mt] = __builtin_amdgcn_mfma_f32_16x16x32_bf16(kf, qf, fzero, 0, 0, 0);
  }
  float vals[16];
  float rmax = -3.0e38f;
#pragma unroll
  for (int mt = 0; mt < 4; ++mt)
#pragma unroll
    for (int r = 0; r < 4; ++r) {
      float v = sacc[mt][r] * SCALE + ((const float*)&mr[mt])[r];
      vals[mt * 4 + r] = v;
      rmax = fmaxf(rmax, v);
    }
  rmax = fmaxf(rmax, __shfl_xor(rmax, 16));
  rmax = fmaxf(rmax, __shfl_xor(rmax, 32));
  float rsum = 0.f;
#pragma unroll
  for (int e = 0; e < 16; ++e) {
    float t = __expf(vals[e] - rmax);
    vals[e] = t;
    rsum += t;
  }
  rsum += __shfl_xor(rsum, 16);
  rsum += __shfl_xor(rsum, 32);
  const float inv = __builtin_amdgcn_rcpf(rsum);
  // pack P rows to bf16 pairs (k ascending within u32)
  unsigned int pk[4][2];
#pragma unroll
  for (int mt = 0; mt < 4; ++mt)
#pragma unroll
    for (int h2 = 0; h2 < 2; ++h2) {
      unsigned short ua = bfbits(tobf(vals[mt * 4 + 2 * h2] * inv));
      unsigned short ub = bfbits(tobf(vals[mt * 4 + 2 * h2 + 1] * inv));
      pk[mt][h2] = (unsigned int)ua | ((unsigned int)ub << 16);
    }
  f32x4 o0 = fzero, o1 = fzero;
#pragma unroll
  for (int ks = 0; ks < 2; ++ks) {
    int e0 = __builtin_amdgcn_ds_bpermute(addr0, (int)pk[2 * ks][0]);
    int e1 = __builtin_amdgcn_ds_bpermute(addr0, (int)pk[2 * ks][1]);
    int e2 = __builtin_amdgcn_ds_bpermute(addr1, (int)pk[2 * ks][0]);
    int e3 = __builtin_amdgcn_ds_bpermute(addr1, (int)pk[2 * ks][1]);
    int f0 = __builtin_amdgcn_ds_bpermute(addr0, (int)pk[2 * ks + 1][0]);
    int f1 = __builtin_amdgcn_ds_bpermute(addr0, (int)pk[2 * ks + 1][1]);
    int f2 = __builtin_amdgcn_ds_bpermute(addr1, (int)pk[2 * ks + 1][0]);
    int f3 = __builtin_amdgcn_ds_bpermute(addr1, (int)pk[2 * ks + 1][1]);
    union { int u[4]; bf16x8 v; } cv;
    cv.u[0] = hi ? f0 : e0;
    cv.u[1] = hi ? f1 : e1;
    cv.u[2] = hi ? f2 : e2;
    cv.u[3] = hi ? f3 : e3;
    bf16x8 pfr = cv.v;
    bf16x8 v0 = *(const bf16x8*)&svh[li * 72 + ks * 32 + lg * 8];
    bf16x8 v1 = *(const bf16x8*)&svh[(16 + li) * 72 + ks * 32 + lg * 8];
    o0 = __builtin_amdgcn_mfma_f32_16x16x32_bf16(v0, pfr, o0, 0, 0, 0);
    o1 = __builtin_amdgcn_mfma_f32_16x16x32_bf16(v1, pfr, o1, 0, 0, 0);
  }
  r0 = (bf16x4){ tobf(o0[0]), tobf(o0[1]), tobf(o0[2]), tobf(o0[3]) };
  r1 = (bf16x4){ tobf(o1[0]), tobf(o1[1]), tobf(o1[2]), tobf(o1[3]) };
}

// Persistent fused kernel: grid 512, 512 threads (8 waves), 16 windows/block.
// LDS = 67072 B -> TWO blocks co-resident per CU (134144 + ~30KB slack),
// 16 waves/CU: cross-block overlap hides barrier drains, HBM bursts, and the
// per-phase imbalance tails. 512-thread shape keeps the allocator's VGPR
// target at 128 (R1-proven, spill-free); all phase live-sets audited <= ~116.
__global__ __launch_bounds__(512, 2) void winattn_fused(
    const float* __restrict__ x,        // [8192,64,192]
    const float* __restrict__ mask,     // [4096,64,64]
    const float* __restrict__ qkv_b,    // [576]
    const float* __restrict__ proj_b,   // [192]
    const bf16_t* __restrict__ qkv_wb,  // [576,192] bf16
    const bf16_t* __restrict__ proj_wb, // [192,192] bf16
    float* __restrict__ out)            // [8192,64,192]
{
  // LDS: 25600 + 27648 + 13824 = 67072 B
  __shared__ __align__(16) bf16_t sx[64 * 200];          // x staging / attn-out
  __shared__ __align__(16) bf16_t shead[3][2 * 64 * 36]; // per LOCAL head: q,k [64][36]
  __shared__ __align__(16) bf16_t svt[3][32 * 72];       // per LOCAL head vT [32][72]

  const int tid  = threadIdx.x;
  const int wave = tid >> 6;
  const int lane = tid & 63;
  const int li   = lane & 15;
  const int lg   = lane >> 4;
  const int bid  = blockIdx.x;
  const bool hi  = (lane >= 32);
  const int addr0 = ((((lane >> 4) & 1) << 5) + li) << 2;  // bperm src, jhi=0
  const int addr1 = addr0 + 64;                            // jhi=1

  const int nu = (wave < 4) ? 2 : 1;   // attn units per wave per group

  // x-staging address map: 6 float4 per thread (512*6 = 3072 = 64*192/4)
  int srow[6], scol[6];
#pragma unroll
  for (int j = 0; j < 6; ++j) {
    int id = tid + 512 * j;
    srow[j] = id / 48;
    scol[j] = (id % 48) * 4;
  }

  // ---- prologue: stage window bid (it=0) into sx ----
  {
    const float4* src = (const float4*)(x + (size_t)bid * 12288);
#pragma unroll
    for (int j = 0; j < 6; ++j) {
      float4 v = src[tid + 512 * j];
      bf16x4 p = { tobf(v.x), tobf(v.y), tobf(v.z), tobf(v.w) };
      *(bf16x4*)&sx[srow[j] * 200 + scol[j]] = p;
    }
  }
  __syncthreads();

  for (int it = 0; it < 16; ++it) {
    const int b = bid + 512 * (it >> 1) + 4096 * (it & 1);  // mask-paired order
    const bool hasNext = (it < 15);

    // ---- G1a: qkv for heads 0-2 ----
    G1_GROUP(0)

    // mask burst for this wave's units (rows depend on nt = u&3 only)
    float4 mreg[2][4];
    {
      const float* maskw = mask + (size_t)(b & 4095) * 4096;
#pragma unroll
      for (int uu = 0; uu < 2; ++uu) {
        if (uu < nu) {
          const int u = (uu == 0) ? wave : (8 + wave);
          const float* mrow = maskw + ((u & 3) * 16 + li) * 64 + lg * 4;
#pragma unroll
          for (int mt = 0; mt < 4; ++mt) mreg[uu][mt] = *(const float4*)(mrow + mt * 16);
        }
      }
    }
    __syncthreads();   // A0: group-0 qkv ready

    // ---- attn group 0: output held in regs (sx still holds x for G1b) ----
    bf16x4 og[2][2];
#pragma unroll
    for (int uu = 0; uu < 2; ++uu) {
      if (uu < nu) {
        const int u = (uu == 0) ? wave : (8 + wave);
        const int hl = u >> 2, nt = u & 3;
        attn_unit(&shead[hl][0], &shead[hl][2304], &svt[hl][0],
                  mreg[uu], li, lg, nt, addr0, addr1, hi, og[uu][0], og[uu][1]);
      }
    }
    __syncthreads();   // B0: group-0 shead/svt consumed -> G1b may overwrite

    // ---- G1b: qkv for heads 3-5 (x re-read from sx) ----
    G1_GROUP(1)

    // reload mask (same rows -> L2 hit)
    {
      const float* maskw = mask + (size_t)(b & 4095) * 4096;
#pragma unroll
      for (int uu = 0; uu < 2; ++uu) {
        if (uu < nu) {
          const int u = (uu == 0) ? wave : (8 + wave);
          const float* mrow = maskw + ((u & 3) * 16 + li) * 64 + lg * 4;
#pragma unroll
          for (int mt = 0; mt < 4; ++mt) mreg[uu][mt] = *(const float4*)(mrow + mt * 16);
        }
      }
    }
    __syncthreads();   // A1: group-1 qkv ready AND x fully consumed (dead)

    // issue next-x prefetch now: latency hides under attn1 + G2
    float4 pf[6];
    if (hasNext) {
      const int bn = bid + 512 * ((it + 1) >> 1) + 4096 * ((it + 1) & 1);
      const float4* src = (const float4*)(x + (size_t)bn * 12288);
#pragma unroll
      for (int j = 0; j < 6; ++j) pf[j] = src[tid + 512 * j];
    }

    // write group-0 attn output into sx (x dead); head cols hl*32
#pragma unroll
    for (int uu = 0; uu < 2; ++uu) {
      if (uu < nu) {
        const int u = (uu == 0) ? wave : (8 + wave);
        const int hl = u >> 2, nt = u & 3;
        bf16_t* so = &sx[(nt * 16 + li) * 200 + hl * 32 + lg * 4];
        *(bf16x4*)&so[0]  = og[uu][0];
        *(bf16x4*)&so[16] = og[uu][1];
      }
    }

    // ---- attn group 1: write output directly (head cols (3+hl)*32) ----
#pragma unroll
    for (int uu = 0; uu < 2; ++uu) {
      if (uu < nu) {
        const int u = (uu == 0) ? wave : (8 + wave);
        const int hl = u >> 2, nt = u & 3;
        bf16x4 r0, r1;
        attn_unit(&shead[hl][0], &shead[hl][2304], &svt[hl][0],
                  mreg[uu], li, lg, nt, addr0, addr1, hi, r0, r1);
        bf16_t* so = &sx[(nt * 16 + li) * 200 + (3 + hl) * 32 + lg * 4];
        *(bf16x4*)&so[0]  = r0;
        *(bf16x4*)&so[16] = r1;
      }
    }
    __syncthreads();   // C: all attn-out in sx

    // ---- GEMM2: out = so @ proj_w^T + proj_b ----
    // 12 (chunk cc, row-half rh) units; wave w -> u=w (+ u=8+w for w<4).
    // ct pair {2cc,2cc+1}: full 128B output sectors. proj weights streamed
    // from L2 per unit (live only inside the unit).
    {
      float* ob = out + (size_t)b * 12288;
#pragma unroll
      for (int uu = 0; uu < 2; ++uu) {
        if (uu < nu) {
          const int u = (uu == 0) ? wave : (8 + wave);
          const int cc = u % 6, rh = u / 6;
          bf16x8 wp0[6], wp1[6];
          {
            const bf16_t* wr0 = proj_wb + (size_t)((2 * cc + 0) * 16 + li) * 192 + lg * 8;
            const bf16_t* wr1 = proj_wb + (size_t)((2 * cc + 1) * 16 + li) * 192 + lg * 8;
#pragma unroll
            for (int kk = 0; kk < 6; ++kk) {
              wp0[kk] = *(const bf16x8*)(wr0 + kk * 32);
              wp1[kk] = *(const bf16x8*)(wr1 + kk * 32);
            }
          }
          const float4 pb0 = *(const float4*)(proj_b + (2 * cc + 0) * 16 + lg * 4);
          const float4 pb1 = *(const float4*)(proj_b + (2 * cc + 1) * 16 + lg * 4);
          const f32x4 fzero = {0.f, 0.f, 0.f, 0.f};
#pragma unroll
          for (int hm = 0; hm < 2; ++hm) {
            const int mt = 2 * rh + hm;
            bf16x8 sb[6];
#pragma unroll
            for (int kk = 0; kk < 6; ++kk)
              sb[kk] = *(const bf16x8*)&sx[(mt * 16 + li) * 200 + kk * 32 + lg * 8];
            f32x4 a0 = fzero, a1 = fzero;
#pragma unroll
            for (int kk = 0; kk < 6; ++kk) {
              a0 = __builtin_amdgcn_mfma_f32_16x16x32_bf16(wp0[kk], sb[kk], a0, 0, 0, 0);
              a1 = __builtin_amdgcn_mfma_f32_16x16x32_bf16(wp1[kk], sb[kk], a1, 0, 0, 0);
            }
            float4 o0 = { a0[0] + pb0.x, a0[1] + pb0.y, a0[2] + pb0.z, a0[3] + pb0.w };
            float4 o1 = { a1[0] + pb1.x, a1[1] + pb1.y, a1[2] + pb1.z, a1[3] + pb1.w };
            float* orow = ob + (size_t)(mt * 16 + li) * 192 + (2 * cc) * 16 + lg * 4;
            *(float4*)(orow)      = o0;
            *(float4*)(orow + 16) = o1;
          }
        }
      }
    }

    if (hasNext) {
      __syncthreads();   // D: all G2 reads of sx complete
#pragma unroll
      for (int j = 0; j < 6; ++j) {
        bf16x4 p = { tobf(pf[j].x), tobf(pf[j].y), tobf(pf[j].z), tobf(pf[j].w) };
        *(bf16x4*)&sx[srow[j] * 200 + scol[j]] = p;
      }
      __syncthreads();   // S: next x staged
    }
  }
}

extern "C" void kernel_launch(void* const* d_in, const int* in_sizes, int n_in,
                              void* d_out, int out_size, void* d_ws, size_t ws_size,
                              hipStream_t stream) {
  const float* x      = (const float*)d_in[0];
  const float* mask   = (const float*)d_in[1];
  const float* qkv_w  = (const float*)d_in[2];
  const float* qkv_b  = (const float*)d_in[3];
  const float* proj_w = (const float*)d_in[4];
  const float* proj_b = (const float*)d_in[5];
  float* out = (float*)d_out;

  bf16_t* qkv_wb  = (bf16_t*)d_ws;
  bf16_t* proj_wb = qkv_wb + 576 * 192;

  cvt_weights<<<432, 256, 0, stream>>>(qkv_w, proj_w, qkv_wb, proj_wb);
  winattn_fused<<<512, 512, 0, stream>>>(x, mask, qkv_b, proj_b, qkv_wb, proj_wb, out);
}

// Round 9
// 474.099 us; speedup vs baseline: 2.3631x; 1.8503x over previous
//
#include <hip/hip_runtime.h>
#include <hip/hip_bf16.h>
#include <stdint.h>

typedef __bf16 bf16_t;
typedef __bf16 bf16x4 __attribute__((ext_vector_type(4)));
typedef __bf16 bf16x8 __attribute__((ext_vector_type(8)));
typedef float  f32x4  __attribute__((ext_vector_type(4)));

#define SCALE 0.17677669529663687f   // (192/6)^-0.5

__device__ __forceinline__ bf16_t tobf(float f) { return (bf16_t)f; }
__device__ __forceinline__ unsigned short bfbits(bf16_t v) {
  union { bf16_t f; unsigned short s; } u; u.f = v; return u.s;
}

__global__ void cvt_weights(const float* __restrict__ qkv_w,
                            const float* __restrict__ proj_w,
                            bf16_t* __restrict__ qkv_wb,
                            bf16_t* __restrict__ proj_wb)
{
  int i = blockIdx.x * 256 + threadIdx.x;
  if (i < 576 * 192) qkv_wb[i] = tobf(qkv_w[i]);
  if (i < 192 * 192) proj_wb[i] = tobf(proj_w[i]);
}

// Persistent fused kernel: grid 256 (1/CU), 512 threads (8 waves), 32 windows/block.
// EXACTLY the R1 structure (proven 648us, VGPR=128, spill-free, near-ideal HBM
// traffic) + two verified low-risk grafts:
//  (1) attn P-transpose done IN-REGISTER via ds_bpermute (verified in R8):
//      removes the P LDS round-trip + lgkmcnt(0) drain per unit; spw deleted.
//  (2) GEMM2 sector-paired: every wave writes both 64B halves of each 128B
//      output sector back-to-back (waves 4-7 remapped to (pair, row-half)).
__global__ __launch_bounds__(512, 2) void winattn_fused(
    const float* __restrict__ x,        // [8192,64,192]
    const float* __restrict__ mask,     // [4096,64,64]
    const float* __restrict__ qkv_b,    // [576]
    const float* __restrict__ proj_b,   // [192]
    const bf16_t* __restrict__ qkv_wb,  // [576,192] bf16
    const bf16_t* __restrict__ proj_wb, // [192,192] bf16
    float* __restrict__ out)            // [8192,64,192]
{
  // LDS: 140288 B (1 block/CU)
  __shared__ __align__(16) bf16_t sbuf[2][64 * 200];     // x staging / attn-out (51200 B)
  __shared__ __align__(16) bf16_t shead[6][2 * 64 * 40]; // per head: q[64][40], k[64][40] (61440 B)
  __shared__ __align__(16) bf16_t svt[6][32 * 72];       // per head vT [32][72] (27648 B)

  const int tid  = threadIdx.x;
  const int wave = tid >> 6;
  const int lane = tid & 63;
  const int li   = lane & 15;
  const int lg   = lane >> 4;
  const bool hi  = (lane >= 32);
  const int addr0 = ((((lane >> 4) & 1) << 5) + li) << 2;  // bperm src lane*4, jhi=0
  const int addr1 = addr0 + 64;                            // jhi=1
  const f32x4 fzero = {0.f, 0.f, 0.f, 0.f};

  // ---- hoist weights (constant across windows) ----
  const int jmax = (wave < 4) ? 5 : 4;     // GEMM1 tiles: nt = wave + 8j < 36
  bf16x8 wf_h[2][6];                       // first 2 GEMM1 tiles (48 VGPR)
#pragma unroll
  for (int j = 0; j < 2; ++j) {
    const int nt = wave + 8 * j;
    const bf16_t* wrow = qkv_wb + (size_t)(nt * 16 + li) * 192 + lg * 8;
#pragma unroll
    for (int kk = 0; kk < 6; ++kk) wf_h[j][kk] = *(const bf16x8*)(wrow + kk * 32);
  }
  // G2 sector-pair mapping: waves 0-3: pair=wave, rows 0-63; waves 4,5: pair 4,
  // rows (wave-4)*32..; waves 6,7: pair 5. Every wave hoists its ct pair.
  const int g2p  = (wave < 4) ? wave : (4 + ((wave - 4) >> 1));
  const int mt0  = (wave < 4) ? 0 : ((wave & 1) ? 2 : 0);
  const int nmt  = (wave < 4) ? 4 : 2;
  bf16x8 wp_h[2][6];                       // proj tiles (48 VGPR)
#pragma unroll
  for (int c = 0; c < 2; ++c) {
    const int ct = 2 * g2p + c;
    const bf16_t* wrow = proj_wb + (size_t)(ct * 16 + li) * 192 + lg * 8;
#pragma unroll
    for (int kk = 0; kk < 6; ++kk) wp_h[c][kk] = *(const bf16x8*)(wrow + kk * 32);
  }

  // x-staging address map
  int srow[6], scol[6];
#pragma unroll
  for (int j = 0; j < 6; ++j) {
    int id = tid + 512 * j;
    srow[j] = id / 48;
    scol[j] = (id % 48) * 4;
  }
  float4 pf[6];

  // ---- prologue: stage window blockIdx.x into sbuf[0] ----
  {
    const float4* src = (const float4*)(x + (size_t)blockIdx.x * 12288);
#pragma unroll
    for (int j = 0; j < 6; ++j) pf[j] = src[tid + 512 * j];
#pragma unroll
    for (int j = 0; j < 6; ++j) {
      bf16x4 p = { tobf(pf[j].x), tobf(pf[j].y), tobf(pf[j].z), tobf(pf[j].w) };
      *(bf16x4*)&sbuf[0][srow[j] * 200 + scol[j]] = p;
    }
  }
  __syncthreads();

  for (int it = 0; it < 32; ++it) {
    const int b   = blockIdx.x + 256 * (it >> 1) + 4096 * (it & 1);  // mask-paired
    const int cur = it & 1;
    bf16_t* sx = sbuf[cur];

    const bool hasNext = (it < 31);
    if (hasNext) {   // prefetch next window's x (regs held through attn phase)
      const int bn = blockIdx.x + 256 * ((it + 1) >> 1) + 4096 * ((it + 1) & 1);
      const float4* src = (const float4*)(x + (size_t)bn * 12288);
#pragma unroll
      for (int j = 0; j < 6; ++j) pf[j] = src[tid + 512 * j];
    }

    // ---- GEMM1: qkv = x @ qkv_w^T + b ----
    for (int j = 0; j < jmax; ++j) {
      const int nt = wave + 8 * j;
      const int typ = nt / 12;             // 0=q 1=k 2=v
      bf16x8 wf[6];
      if (j < 2) {
#pragma unroll
        for (int kk = 0; kk < 6; ++kk) wf[kk] = wf_h[j][kk];
      } else {
        const bf16_t* wrow = qkv_wb + (size_t)(nt * 16 + li) * 192 + lg * 8;
#pragma unroll
        for (int kk = 0; kk < 6; ++kk) wf[kk] = *(const bf16x8*)(wrow + kk * 32);
      }
      if (typ < 2) {
        // swapped: D[wcol][token]; lane -> 4 consecutive d of one token
        float4 qb4 = *(const float4*)(qkv_b + nt * 16 + lg * 4);
        const int cc = (nt - typ * 12) * 16 + lg * 4;
        const int h = cc >> 5, dd = cc & 31;
        bf16_t* dst = &shead[h][typ * 2560 + dd];
#pragma unroll
        for (int mt = 0; mt < 4; ++mt) {
          f32x4 a = fzero;
#pragma unroll
          for (int kk = 0; kk < 6; ++kk) {
            bf16x8 xb = *(const bf16x8*)&sx[(mt * 16 + li) * 200 + kk * 32 + lg * 8];
            a = __builtin_amdgcn_mfma_f32_16x16x32_bf16(wf[kk], xb, a, 0, 0, 0);
          }
          bf16x4 pk = { tobf(a[0] + qb4.x), tobf(a[1] + qb4.y),
                        tobf(a[2] + qb4.z), tobf(a[3] + qb4.w) };
          *(bf16x4*)&dst[(mt * 16 + li) * 40] = pk;
        }
      } else {
        // direct: D[token][wcol]; store vT[d][tok] bf16x4 along tok
        const float vb = qkv_b[nt * 16 + li];
        const int cc = (nt - 24) * 16 + li;
        const int h = cc >> 5, dd = cc & 31;
        bf16_t* dst = &svt[h][dd * 72];
#pragma unroll
        for (int mt = 0; mt < 4; ++mt) {
          f32x4 a = fzero;
#pragma unroll
          for (int kk = 0; kk < 6; ++kk) {
            bf16x8 xb = *(const bf16x8*)&sx[(mt * 16 + li) * 200 + kk * 32 + lg * 8];
            a = __builtin_amdgcn_mfma_f32_16x16x32_bf16(xb, wf[kk], a, 0, 0, 0);
          }
          bf16x4 pk = { tobf(a[0] + vb), tobf(a[1] + vb),
                        tobf(a[2] + vb), tobf(a[3] + vb) };
          *(bf16x4*)&dst[mt * 16 + lg * 4] = pk;
        }
      }
    }
    __syncthreads();   // barrier A: qkv ready

    // ---- mask burst: all 3 units' rows, one latency ----
    float4 mreg[3][4];
    {
      const float* maskw = mask + (size_t)(b & 4095) * 4096;
#pragma unroll
      for (int uu = 0; uu < 3; ++uu) {
        const int ntu = (wave * 3 + uu) & 3;
        const float* mrow = maskw + (ntu * 16 + li) * 64 + lg * 4;
#pragma unroll
        for (int mt = 0; mt < 4; ++mt) mreg[uu][mt] = *(const float4*)(mrow + mt * 16);
      }
    }

    // ---- attention: 24 units, 3 per wave; P transposed IN-REGISTER ----
#pragma unroll
    for (int uu = 0; uu < 3; ++uu) {
      const int unit = wave * 3 + uu;
      const int h  = unit >> 2;
      const int nt = unit & 3;
      const bf16_t* sq = &shead[h][0];
      const bf16_t* sk = &shead[h][2560];
      bf16x8 qf = *(const bf16x8*)&sq[(nt * 16 + li) * 40 + lg * 8];
      f32x4 sacc[4];
#pragma unroll
      for (int mt = 0; mt < 4; ++mt) {
        bf16x8 kf = *(const bf16x8*)&sk[(mt * 16 + li) * 40 + lg * 8];
        sacc[mt] = __builtin_amdgcn_mfma_f32_16x16x32_bf16(kf, qf, fzero, 0, 0, 0);
      }
      float vals[16];
      float rmax = -3.0e38f;
#pragma unroll
      for (int mt = 0; mt < 4; ++mt)
#pragma unroll
        for (int r = 0; r < 4; ++r) {
          float v = sacc[mt][r] * SCALE + ((const float*)&mreg[uu][mt])[r];
          vals[mt * 4 + r] = v;
          rmax = fmaxf(rmax, v);
        }
      rmax = fmaxf(rmax, __shfl_xor(rmax, 16));
      rmax = fmaxf(rmax, __shfl_xor(rmax, 32));
      float rsum = 0.f;
#pragma unroll
      for (int e = 0; e < 16; ++e) {
        float t = __expf(vals[e] - rmax);
        vals[e] = t;
        rsum += t;
      }
      rsum += __shfl_xor(rsum, 16);
      rsum += __shfl_xor(rsum, 32);
      const float inv = __builtin_amdgcn_rcpf(rsum);
      // pack P rows to bf16 pairs (k ascending within u32)
      unsigned int pk[4][2];
#pragma unroll
      for (int mt = 0; mt < 4; ++mt)
#pragma unroll
        for (int h2 = 0; h2 < 2; ++h2) {
          unsigned short ua = bfbits(tobf(vals[mt * 4 + 2 * h2] * inv));
          unsigned short ub = bfbits(tobf(vals[mt * 4 + 2 * h2 + 1] * inv));
          pk[mt][h2] = (unsigned int)ua | ((unsigned int)ub << 16);
        }
      // in-register transpose (R8-verified): B-operand lane (li,lg) needs
      // P[q=li][k=32ks+8lg+e]; fixed 4-group lane exchange via ds_bpermute.
      f32x4 o0 = fzero, o1 = fzero;
#pragma unroll
      for (int ks = 0; ks < 2; ++ks) {
        int e0 = __builtin_amdgcn_ds_bpermute(addr0, (int)pk[2 * ks][0]);
        int e1 = __builtin_amdgcn_ds_bpermute(addr0, (int)pk[2 * ks][1]);
        int e2 = __builtin_amdgcn_ds_bpermute(addr1, (int)pk[2 * ks][0]);
        int e3 = __builtin_amdgcn_ds_bpermute(addr1, (int)pk[2 * ks][1]);
        int f0 = __builtin_amdgcn_ds_bpermute(addr0, (int)pk[2 * ks + 1][0]);
        int f1 = __builtin_amdgcn_ds_bpermute(addr0, (int)pk[2 * ks + 1][1]);
        int f2 = __builtin_amdgcn_ds_bpermute(addr1, (int)pk[2 * ks + 1][0]);
        int f3 = __builtin_amdgcn_ds_bpermute(addr1, (int)pk[2 * ks + 1][1]);
        union { int u[4]; bf16x8 v; } cv;
        cv.u[0] = hi ? f0 : e0;
        cv.u[1] = hi ? f1 : e1;
        cv.u[2] = hi ? f2 : e2;
        cv.u[3] = hi ? f3 : e3;
        bf16x8 pfr = cv.v;
        bf16x8 v0  = *(const bf16x8*)&svt[h][li * 72 + ks * 32 + lg * 8];
        bf16x8 v1  = *(const bf16x8*)&svt[h][(16 + li) * 72 + ks * 32 + lg * 8];
        o0 = __builtin_amdgcn_mfma_f32_16x16x32_bf16(v0, pfr, o0, 0, 0, 0);
        o1 = __builtin_amdgcn_mfma_f32_16x16x32_bf16(v1, pfr, o1, 0, 0, 0);
      }
      bf16x4 p0 = { tobf(o0[0]), tobf(o0[1]), tobf(o0[2]), tobf(o0[3]) };
      bf16x4 p1 = { tobf(o1[0]), tobf(o1[1]), tobf(o1[2]), tobf(o1[3]) };
      bf16_t* so = &sx[(nt * 16 + li) * 200 + h * 32 + lg * 4];
      *(bf16x4*)&so[0]  = p0;
      *(bf16x4*)&so[16] = p1;
    }

    // write prefetched next-window x into the other buffer
    if (hasNext) {
      bf16_t* nx = sbuf[cur ^ 1];
#pragma unroll
      for (int j = 0; j < 6; ++j) {
        bf16x4 p = { tobf(pf[j].x), tobf(pf[j].y), tobf(pf[j].z), tobf(pf[j].w) };
        *(bf16x4*)&nx[srow[j] * 200 + scol[j]] = p;
      }
    }
    __syncthreads();   // barrier B: attn-out + next-x staged

    // ---- GEMM2: out = so @ proj_w^T + proj_b (sector-paired, weights in regs) ----
    // Every wave computes BOTH ct tiles of its 128B sector pair and stores the
    // two 64B halves back-to-back -> full-line writes from a single wave.
    {
      float* ob = out + (size_t)b * 12288;
      const float4 pb0 = *(const float4*)(proj_b + (2 * g2p + 0) * 16 + lg * 4);
      const float4 pb1 = *(const float4*)(proj_b + (2 * g2p + 1) * 16 + lg * 4);
      for (int m = 0; m < nmt; ++m) {
        const int mt = mt0 + m;
        bf16x8 sb[6];
#pragma unroll
        for (int kk = 0; kk < 6; ++kk)
          sb[kk] = *(const bf16x8*)&sx[(mt * 16 + li) * 200 + kk * 32 + lg * 8];
        f32x4 a0 = fzero, a1 = fzero;
#pragma unroll
        for (int kk = 0; kk < 6; ++kk) {
          a0 = __builtin_amdgcn_mfma_f32_16x16x32_bf16(wp_h[0][kk], sb[kk], a0, 0, 0, 0);
          a1 = __builtin_amdgcn_mfma_f32_16x16x32_bf16(wp_h[1][kk], sb[kk], a1, 0, 0, 0);
        }
        float4 o0 = { a0[0] + pb0.x, a0[1] + pb0.y, a0[2] + pb0.z, a0[3] + pb0.w };
        float4 o1 = { a1[0] + pb1.x, a1[1] + pb1.y, a1[2] + pb1.z, a1[3] + pb1.w };
        float* orow = ob + (size_t)(mt * 16 + li) * 192 + (2 * g2p) * 16 + lg * 4;
        *(float4*)(orow)      = o0;
        *(float4*)(orow + 16) = o1;
      }
    }
    // no barrier: next window's GEMM1 touches shead/svt only and reads
    // sbuf[cur^1]; the next prefetch-write to sbuf[cur] is ordered by barrier A.
  }
}

extern "C" void kernel_launch(void* const* d_in, const int* in_sizes, int n_in,
                              void* d_out, int out_size, void* d_ws, size_t ws_size,
                              hipStream_t stream) {
  const float* x      = (const float*)d_in[0];
  const float* mask   = (const float*)d_in[1];
  const float* qkv_w  = (const float*)d_in[2];
  const float* qkv_b  = (const float*)d_in[3];
  const float* proj_w = (const float*)d_in[4];
  const float* proj_b = (const float*)d_in[5];
  float* out = (float*)d_out;

  bf16_t* qkv_wb  = (bf16_t*)d_ws;
  bf16_t* proj_wb = qkv_wb + 576 * 192;

  cvt_weights<<<432, 256, 0, stream>>>(qkv_w, proj_w, qkv_wb, proj_wb);
  winattn_fused<<<256, 512, 0, stream>>>(x, mask, qkv_b, proj_b, qkv_wb, proj_wb, out);
}